// Round 12
// baseline (386.877 us; speedup 1.0000x reference)
//
#include <hip/hip_runtime.h>
#include <math.h>

#define NNODES 100000
#define NEDGES 1600000
#define NPOS   4096      // 32 seqs * 128 steps
#define NSEQ   32
#define TSTEPS 128

typedef float f32x4 __attribute__((ext_vector_type(4)));
typedef unsigned u32x4 __attribute__((ext_vector_type(4)));
typedef _Float16 h2v __attribute__((ext_vector_type(2)));

// ---- ws layout (bytes) ----
#define OFF_SLOT   0          // int[100000]  (dead after k_pregemm)
#define OFF_AGG    400128     // float[4096*128] (dead after k_pregemm; overlaid by wh16)
#define OFF_CNT    2497280    // float[4096]
#define OFF_WF     2513664    // float[1024*128]
#define OFF_BIASF  3037952    // float[1024]
#define OFF_PREG   3042048    // float[128][32s][8m][4q][32d]
#define OFF_HS     19819264   // float[129][32][256]
// fp16 weight images overlay the dead agg region (valid only after k_pregemm).
// Movement model (R10/R11 measured): step cost = max over pipes of bytes/BW
// (DS ~85 B/cyc, VMEM ~100 B/cyc, VALU 1024 cyc) IF overlapped. Registers are
// the only free storage (cap 128 VGPR @512thr). Split per thread (64 quads):
//   16 quads REG (131 KB/CU) + 16 quads LDS (131 KB) + 32 quads L2-stream
//   (262 KB/step).
//   wR: u32[64][512]     131072 B
//   wL: u32x4[16][512]   131072 B
//   wS: u32x4[32][512]   262144 B
#define OFF_WR  OFF_AGG
#define OFF_WL  (OFF_AGG + 131072)
#define OFF_WS  (OFF_AGG + 262144)

// fp16 dot2 with f32 accumulate: D = w.h[0]*h.h[0] + w.h[1]*h.h[1] + acc.
static __device__ __forceinline__ float fdot2(unsigned w, unsigned h, float acc) {
#if __has_builtin(__builtin_amdgcn_fdot2)
  h2v wv, hv;
  __builtin_memcpy(&wv, &w, 4);
  __builtin_memcpy(&hv, &h, 4);
  return __builtin_amdgcn_fdot2(wv, hv, acc, false);
#else
  asm("v_dot2_f32_f16 %0, %1, %2, %0" : "+v"(acc) : "v"(w), "v"(h));
  return acc;
#endif
}

// one weight quad (4 packed pairs = 8 k) against one h quad
static __device__ __forceinline__ float dotq(u32x4 w, u32x4 h, float a) {
  a = fdot2(w[0], h[0], a);
  a = fdot2(w[1], h[1], a);
  a = fdot2(w[2], h[2], a);
  a = fdot2(w[3], h[3], a);
  return a;
}

// ---------------- init ----------------
__global__ void k_init(int* slotmap, float* agg, float* cnt, float* hs0) {
  int i = blockIdx.x * blockDim.x + threadIdx.x;
  int stride = gridDim.x * blockDim.x;
  for (int idx = i; idx < 4096 * 128; idx += stride) agg[idx] = 0.f;
  for (int idx = i; idx < NNODES; idx += stride) slotmap[idx] = -1;
  for (int idx = i; idx < 4096; idx += stride) cnt[idx] = 0.f;
  for (int idx = i; idx < 8192; idx += stride) hs0[idx] = 0.f;
}

// ---------------- mark needed nodes ----------------
__global__ void k_mark(const int* __restrict__ input_ids, int* __restrict__ slotmap) {
  int p = blockIdx.x * blockDim.x + threadIdx.x;
  if (p < NPOS) atomicCAS(&slotmap[input_ids[p]], -1, p);
}

// ---------------- edge pass: masked segment-sum ----------------
__global__ void k_edge(const int* __restrict__ src, const int* __restrict__ dst,
                       const float* __restrict__ ev, const float* __restrict__ emb,
                       const int* __restrict__ slotmap,
                       float* __restrict__ agg, float* __restrict__ cnt) {
  int e = blockIdx.x * 256 + threadIdx.x;
  int lane = threadIdx.x & 63;
  int d = dst[e];
  int slot = slotmap[d];
  int sn = 0; float vv = 0.f;
  if (slot >= 0) { sn = src[e]; vv = ev[e]; }
  unsigned long long m = __ballot(slot >= 0);
  while (m) {
    int j = __ffsll(m) - 1;
    m &= m - 1;
    int sl = __shfl(slot, j);
    int s2 = __shfl(sn, j);
    float v = __shfl(vv, j);
    float2 em = *(const float2*)&emb[(size_t)s2 * 128 + 2 * lane];
    atomicAdd(&agg[sl * 128 + 2 * lane],     em.x * v);
    atomicAdd(&agg[sl * 128 + 2 * lane + 1], em.y * v);
    if (lane == 0) atomicAdd(&cnt[sl], 1.f);
  }
}

// ---------------- divide by count ----------------
__global__ void k_div(float* __restrict__ agg, const float* __restrict__ cnt) {
  int i = blockIdx.x * blockDim.x + threadIdx.x;
  agg[i] /= fmaxf(cnt[i >> 7], 1.f);
}

// ---------------- fuse W_f = w_ih @ W1, bias_f ----------------
__global__ void k_fuse(const float* __restrict__ w_ih, const float* __restrict__ W1,
                       const float* __restrict__ b1, const float* __restrict__ b_ih,
                       const float* __restrict__ b_hh,
                       float* __restrict__ Wf, float* __restrict__ bf) {
  int row = blockIdx.x;
  int e = threadIdx.x;
  float acc = 0.f;
  for (int m2 = 0; m2 < 256; ++m2) acc += w_ih[row * 256 + m2] * W1[m2 * 128 + e];
  Wf[row * 128 + e] = acc;
  if (e == 0) {
    float bacc = b_ih[row] + b_hh[row];
    for (int m2 = 0; m2 < 256; ++m2) bacc += w_ih[row * 256 + m2] * b1[m2];
    bf[row] = bacc;
  }
}

// ---------------- pre-gates GEMM: preg[t][s][m][q][32d] ----------------
__global__ __launch_bounds__(256, 2) void k_pregemm(
    const float* __restrict__ hnode, const float* __restrict__ Wf,
    const float* __restrict__ bf, const int* __restrict__ slotmap,
    const int* __restrict__ input_ids, float* __restrict__ preg) {
  __shared__ float Ash[64][132];
  __shared__ float Bsh[64][132];
  __shared__ int slots[64];
  int tid = threadIdx.x;
  int bm = (blockIdx.x & 63) * 64;
  int bn = (blockIdx.x >> 6) * 64;
  if (tid < 64) slots[tid] = slotmap[input_ids[bm + tid]];
  __syncthreads();
#pragma unroll
  for (int i = 0; i < 8; ++i) {
    int idx = tid + 256 * i;
    int r = idx >> 5, c = idx & 31;
    *(float4*)&Ash[r][c * 4] = *(const float4*)&hnode[slots[r] * 128 + c * 4];
    *(float4*)&Bsh[r][c * 4] = *(const float4*)&Wf[(bn + r) * 128 + c * 4];
  }
  __syncthreads();
  int tx = tid & 15, ty = tid >> 4;
  float acc[4][4] = {};
  for (int k = 0; k < 128; k += 4) {
    float4 a[4], bb[4];
#pragma unroll
    for (int i = 0; i < 4; ++i) a[i] = *(const float4*)&Ash[tx + 16 * i][k];
#pragma unroll
    for (int j = 0; j < 4; ++j) bb[j] = *(const float4*)&Bsh[ty + 16 * j][k];
#pragma unroll
    for (int i = 0; i < 4; ++i)
#pragma unroll
      for (int j = 0; j < 4; ++j)
        acc[i][j] += a[i].x * bb[j].x + a[i].y * bb[j].y + a[i].z * bb[j].z + a[i].w * bb[j].w;
  }
#pragma unroll
  for (int j = 0; j < 4; ++j) {
    int row = bn + ty + 16 * j;
    float bias = bf[row];
    int q  = row >> 8;
    int mm = (row >> 5) & 7;
    int dl = row & 31;
#pragma unroll
    for (int i = 0; i < 4; ++i) {
      int p = bm + tx + 16 * i;
      int s = p >> 7, tt = p & 127;
      preg[(((size_t)(tt * 32 + s) * 8 + mm) * 4 + q) * 32 + dl] = acc[i][j] + bias;
    }
  }
}

// ---------------- w_hh f32 -> packed fp16 three-way images (RNE) ----------------
// k_lstm mapping: tid = kseg*128 + dd2 owns dims d0=2dd2, d1=2dd2+1, k-slice
// [64*kseg, 64*kseg+64). Row r = (d&1)*4 + q, pair p 0..31, phase b = p>>4,
// quad i = (p>>2)&3, lane l = p&3:
//   i==0 -> REG    quad qr = b*8 + r           (16 quads)
//   i==1 -> LDS    quad lc = b*8 + r           (16 quads)
//   i>=2 -> STREAM quad sc = (b*8+r)*2 + (i-2) (32 quads)
__global__ void k_wcvt(const float* __restrict__ w_hh, unsigned* __restrict__ wR,
                       unsigned* __restrict__ wL, unsigned* __restrict__ wS) {
  int idx = blockIdx.x * 256 + threadIdx.x;   // 0..131071
  int row = idx >> 7;          // q*256 + dout
  int j   = idx & 127;         // pair index (k = 2j, 2j+1)
  float x0 = w_hh[(size_t)row * 256 + 2 * j];
  float x1 = w_hh[(size_t)row * 256 + 2 * j + 1];
  union { _Float16 f[2]; unsigned u; } pk;
  pk.f[0] = (_Float16)x0;
  pk.f[1] = (_Float16)x1;
  int q = row >> 8, dout = row & 255;
  int dim2 = dout & 1, dd2 = dout >> 1;
  int r = dim2 * 4 + q;
  int kseg = j >> 5, p = j & 31;
  int b = p >> 4, i = (p >> 2) & 3, l = p & 3;
  int tid = kseg * 128 + dd2;
  if (i == 0) {
    wR[((b * 8 + r) * 4 + l) * 512 + tid] = pk.u;
  } else if (i == 1) {
    wL[((b * 8 + r) * 512 + tid) * 4 + l] = pk.u;
  } else {
    wS[(((b * 8 + r) * 2 + (i - 2)) * 512 + tid) * 4 + l] = pk.u;
  }
}

// ---------------- LSTM: one sequence per CU; reg/LDS/L2-stream weight split ----
// R11 post-mortem: pipes SERIALIZED (step = DS+VMEM+VALU summed) because the
// 30-live-quad unroll left no prefetch distance, and accb's 32B stride caused
// 590K bank conflicts. Fixes: (1) rolling 2-row stream prefetch (6 live quads,
// load->use gap ~2 rows ~ L2 latency), (2) accb split into two 16B-stride
// arrays (R10's conflict-free pattern), (3) clean row loop: per row per phase
// 1 reg quad + 1 LDS quad + 2 stream quads vs 4 h quads. Target: step = max
// (VMEM 2620, DS ~2200, VALU ~1300) + tail ~= 2.9k cyc ~= 1.2us.
__global__ __launch_bounds__(512) void k_lstm(
    const unsigned* __restrict__ wR, const unsigned* __restrict__ wL,
    const unsigned* __restrict__ wS, const float* __restrict__ preg,
    float* __restrict__ hs) {
  __shared__ __align__(16) unsigned whL[16 * 512 * 4];   // 131072 B
  __shared__ __align__(16) unsigned h16[128];            // 512 B: 256 fp16 h
  __shared__ __align__(16) float accbA[3 * 128 * 4];     // 6144 B (16B stride)
  __shared__ __align__(16) float accbB[3 * 128 * 4];     // 6144 B
  const int tid = threadIdx.x;
  const int s = blockIdx.x;
  const int kseg = tid >> 7;       // 0..3 : k-slice [64*kseg, 64*kseg+64)
  const int dd2 = tid & 127;       // dim pair: d0=2dd2, d1=2dd2+1
  const bool owner = (kseg == 0);

  // ---- prologue: 16 quads -> VGPRs, 16 quads -> LDS (coalesced) ----
  u32x4 rq[16];
#pragma unroll
  for (int qr = 0; qr < 16; ++qr)
#pragma unroll
    for (int l = 0; l < 4; ++l)
      rq[qr][l] = wR[(qr * 4 + l) * 512 + tid];
  {
    const u32x4* src = (const u32x4*)wL;
    u32x4* dst = (u32x4*)whL;
#pragma unroll
    for (int lc = 0; lc < 16; ++lc)
      dst[lc * 512 + tid] = src[lc * 512 + tid];
  }
  if (tid < 128) h16[tid] = 0u;    // h(0) = 0 (fp16 pair)
  float c0s = 0.f, c1s = 0.f;      // cell states for d0, d1 (owners)
  __syncthreads();

  const u32x4* hqp = (const u32x4*)h16 + kseg * 8;  // 8 h-quads for this kseg
  const u32x4* lq  = (const u32x4*)whL + tid;       // quad lc at lq[lc*512]
  const u32x4* sq  = (const u32x4*)wS + tid;        // quad sc at sq[sc*512]

  for (int t = 0; t < TSTEPS; ++t) {
    // owner pre-gates: d0,d1 adjacent in preg's dl dimension -> float2
    float2 pg0, pg1, pg2, pg3;
    if (owner) {
      const float* pb = preg + (((size_t)(t * 32 + s) * 8 + (dd2 >> 4)) * 4) * 32
                        + ((2 * dd2) & 31);
      pg0 = *(const float2*)&pb[0];
      pg1 = *(const float2*)&pb[32];
      pg2 = *(const float2*)&pb[64];
      pg3 = *(const float2*)&pb[96];
    }
    float a[8] = {0.f, 0.f, 0.f, 0.f, 0.f, 0.f, 0.f, 0.f};
#pragma unroll
    for (int b = 0; b < 2; ++b) {
      u32x4 h0 = hqp[b * 4 + 0], h1 = hqp[b * 4 + 1];
      u32x4 h2 = hqp[b * 4 + 2], h3 = hqp[b * 4 + 3];
      // rolling 2-row stream prefetch (6 live quads max)
      u32x4 p0A = sq[(b * 16 + 0) * 512], p0B = sq[(b * 16 + 1) * 512];
      u32x4 p1A = sq[(b * 16 + 2) * 512], p1B = sq[(b * 16 + 3) * 512];
#pragma unroll
      for (int r = 0; r < 8; ++r) {
        u32x4 nA, nB;
        if (r < 6) {
          nA = sq[(b * 16 + (r + 2) * 2) * 512];
          nB = sq[(b * 16 + (r + 2) * 2 + 1) * 512];
        }
        float ar = a[r];
        ar = dotq(rq[b * 8 + r], h0, ar);          // i=0 (registers)
        ar = dotq(lq[(b * 8 + r) * 512], h1, ar);  // i=1 (LDS)
        ar = dotq(p0A, h2, ar);                    // i=2 (stream)
        ar = dotq(p0B, h3, ar);                    // i=3 (stream)
        a[r] = ar;
        p0A = p1A; p0B = p1B; p1A = nA; p1B = nB;
      }
    }
    // ---- publish partials (ksegs 1..3), 16B-stride conflict-free ----
    if (!owner) {
      f32x4 pA; pA.x = a[0]; pA.y = a[1]; pA.z = a[2]; pA.w = a[3];
      f32x4 pB; pB.x = a[4]; pB.y = a[5]; pB.z = a[6]; pB.w = a[7];
      *(f32x4*)&accbA[((kseg - 1) * 128 + dd2) * 4] = pA;
      *(f32x4*)&accbB[((kseg - 1) * 128 + dd2) * 4] = pB;
    }
    __syncthreads();                 // partials visible; h16 reads done
    if (owner) {
#pragma unroll
      for (int ks = 0; ks < 3; ++ks) {
        f32x4 pA = *(const f32x4*)&accbA[(ks * 128 + dd2) * 4];
        f32x4 pB = *(const f32x4*)&accbB[(ks * 128 + dd2) * 4];
        a[0] += pA.x; a[1] += pA.y; a[2] += pA.z; a[3] += pA.w;
        a[4] += pB.x; a[5] += pB.y; a[6] += pB.z; a[7] += pB.w;
      }
      float gi0 = a[0] + pg0.x, gf0 = a[1] + pg1.x;
      float gg0 = a[2] + pg2.x, go0 = a[3] + pg3.x;
      float gi1 = a[4] + pg0.y, gf1 = a[5] + pg1.y;
      float gg1 = a[6] + pg2.y, go1 = a[7] + pg3.y;
      float si0 = 1.f / (1.f + expf(-gi0));
      float sf0 = 1.f / (1.f + expf(-gf0));
      float so0 = 1.f / (1.f + expf(-go0));
      float cc0 = sf0 * c0s + si0 * tanhf(gg0);
      float hh0 = so0 * tanhf(cc0);
      c0s = cc0;
      float si1 = 1.f / (1.f + expf(-gi1));
      float sf1 = 1.f / (1.f + expf(-gf1));
      float so1 = 1.f / (1.f + expf(-go1));
      float cc1 = sf1 * c1s + si1 * tanhf(gg1);
      float hh1 = so1 * tanhf(cc1);
      c1s = cc1;
      union { _Float16 f[2]; unsigned u; } hp;
      hp.f[0] = (_Float16)hh0;
      hp.f[1] = (_Float16)hh1;
      h16[dd2] = hp.u;                                         // next-step h
      float2 hv; hv.x = hh0; hv.y = hh1;
      *(float2*)&hs[(size_t)(t + 1) * 8192 + s * 256 + 2 * dd2] = hv;  // history
    }
    __syncthreads();                 // new h16 + accb reuse protected
  }
}

// ---------------- final: scores, softmax, BCE, argmax ----------------
__global__ void k_final(const float* __restrict__ hs, const int* __restrict__ mask,
                        const float* __restrict__ labels, const float* __restrict__ W2,
                        const float* __restrict__ b2, float* __restrict__ out) {
  __shared__ float scores[32];
  __shared__ float errpart[8];
  int tid = threadIdx.x;
  if (tid < 32) {
    int len = 0;
    for (int t = 0; t < 128; ++t) len += mask[tid * 128 + t];
    if (len < 1) len = 1;
    const float* hl = hs + (size_t)len * 8192 + tid * 256;
    float acc = b2[0];
    for (int k = 0; k < 256; ++k) acc += hl[k] * W2[k];
    scores[tid] = acc;
  }
  __syncthreads();
  if (tid < 8) {
    float sc[4];
#pragma unroll
    for (int i = 0; i < 4; ++i) sc[i] = scores[tid * 4 + i];
    float mx = fmaxf(fmaxf(sc[0], sc[1]), fmaxf(sc[2], sc[3]));
    float ex[4], ssum = 0.f;
#pragma unroll
    for (int i = 0; i < 4; ++i) { ex[i] = expf(sc[i] - mx); ssum += ex[i]; }
    float esum = 0.f; int am = 0; float best = -1e30f;
#pragma unroll
    for (int i = 0; i < 4; ++i) {
      float p = ex[i] / ssum;
      float li = labels[tid * 4 + i];
      esum += fmaxf(p, 0.f) - p * li + log1pf(expf(-fabsf(p)));
      if (p > best) { best = p; am = i; }
    }
    errpart[tid] = esum;
    out[1 + tid] = (float)am;
  }
  __syncthreads();
  if (tid == 0) {
    float e = 0.f;
    for (int i = 0; i < 8; ++i) e += errpart[i];
    out[0] = e / 32.f;
  }
}

extern "C" void kernel_launch(void* const* d_in, const int* in_sizes, int n_in,
                              void* d_out, int out_size, void* d_ws, size_t ws_size,
                              hipStream_t stream) {
  const int*   input_ids  = (const int*)d_in[0];
  const int*   input_mask = (const int*)d_in[1];
  const float* labels     = (const float*)d_in[2];
  const int*   src        = (const int*)d_in[3];
  const int*   dst        = (const int*)d_in[4];
  const float* ev         = (const float*)d_in[5];
  const float* node_emb   = (const float*)d_in[6];
  const float* W1         = (const float*)d_in[7];
  const float* b1         = (const float*)d_in[8];
  const float* w_ih       = (const float*)d_in[9];
  const float* w_hh       = (const float*)d_in[10];
  const float* b_ih       = (const float*)d_in[11];
  const float* b_hh       = (const float*)d_in[12];
  const float* W2         = (const float*)d_in[13];
  const float* b2         = (const float*)d_in[14];
  float* out = (float*)d_out;
  char* ws = (char*)d_ws;
  int*      slotmap = (int*)(ws + OFF_SLOT);
  float*    agg     = (float*)(ws + OFF_AGG);
  float*    cnt     = (float*)(ws + OFF_CNT);
  float*    Wf      = (float*)(ws + OFF_WF);
  float*    biasf   = (float*)(ws + OFF_BIASF);
  float*    preg    = (float*)(ws + OFF_PREG);
  float*    hs      = (float*)(ws + OFF_HS);
  unsigned* wRimg   = (unsigned*)(ws + OFF_WR);
  unsigned* wLimg   = (unsigned*)(ws + OFF_WL);
  unsigned* wSimg   = (unsigned*)(ws + OFF_WS);

  hipLaunchKernelGGL(k_init,    dim3(2048), dim3(256), 0, stream, slotmap, agg, cnt, hs);
  hipLaunchKernelGGL(k_mark,    dim3(16),   dim3(256), 0, stream, input_ids, slotmap);
  hipLaunchKernelGGL(k_edge,    dim3(6250), dim3(256), 0, stream, src, dst, ev, node_emb, slotmap, agg, cnt);
  hipLaunchKernelGGL(k_div,     dim3(2048), dim3(256), 0, stream, agg, cnt);
  hipLaunchKernelGGL(k_fuse,    dim3(1024), dim3(128), 0, stream, w_ih, W1, b1, b_ih, b_hh, Wf, biasf);
  hipLaunchKernelGGL(k_pregemm, dim3(1024), dim3(256), 0, stream, agg, Wf, biasf, slotmap, input_ids, preg);
  hipLaunchKernelGGL(k_wcvt,    dim3(512),  dim3(256), 0, stream, w_hh, wRimg, wLimg, wSimg);
  hipLaunchKernelGGL(k_lstm,    dim3(NSEQ), dim3(512), 0, stream, wRimg, wLimg, wSimg, preg, hs);
  hipLaunchKernelGGL(k_final,   dim3(1),    dim3(64),  0, stream, hs, input_mask, labels, W2, b2, out);
}

// Round 13
// 334.303 us; speedup vs baseline: 1.1573x; 1.1573x over previous
//
#include <hip/hip_runtime.h>
#include <math.h>

#define NNODES 100000
#define NEDGES 1600000
#define NPOS   4096      // 32 seqs * 128 steps
#define NSEQ   32
#define TSTEPS 128

typedef float f32x4 __attribute__((ext_vector_type(4)));
typedef unsigned u32x4 __attribute__((ext_vector_type(4)));
typedef _Float16 h2v __attribute__((ext_vector_type(2)));

// ---- ws layout (bytes) ----
#define OFF_SLOT   0          // int[100000]  (dead after k_pregemm)
#define OFF_AGG    400128     // float[4096*128] (dead after k_pregemm; overlaid by wh16)
#define OFF_CNT    2497280    // float[4096]
#define OFF_WF     2513664    // float[1024*128]
#define OFF_BIASF  3037952    // float[1024]
#define OFF_PREG   3042048    // float[128][32s][8m][4q][32d]
#define OFF_HS     19819264   // float[129][32][256]
// fp16 weight images overlay the dead agg region (valid only after k_pregemm).
// Measured model (R10-R12): 16 waves (1024thr) overlap VMEM at ~96% of the
// ~100 B/cyc floor; 8 waves (512thr) run at ~2x floor regardless of prefetch.
// VGPR budget @1024thr = 64 (hard). So: R10 geometry, split sized to fit:
//   wR: u32[24][1024]    6 quads/thread register-resident    98304 B
//   wL: u32x4[9][1024]   9 quads/thread LDS-resident        147456 B
//   wS: u32x4[17][1024]  17 quads/thread L2-streamed/step   278528 B
#define OFF_WR  OFF_AGG
#define OFF_WL  (OFF_AGG + 98304)
#define OFF_WS  (OFF_AGG + 245760)

// fp16 dot2 with f32 accumulate: D = w.h[0]*h.h[0] + w.h[1]*h.h[1] + acc.
static __device__ __forceinline__ float fdot2(unsigned w, unsigned h, float acc) {
#if __has_builtin(__builtin_amdgcn_fdot2)
  h2v wv, hv;
  __builtin_memcpy(&wv, &w, 4);
  __builtin_memcpy(&hv, &h, 4);
  return __builtin_amdgcn_fdot2(wv, hv, acc, false);
#else
  asm("v_dot2_f32_f16 %0, %1, %2, %0" : "+v"(acc) : "v"(w), "v"(h));
  return acc;
#endif
}

// one weight quad (4 packed pairs = 8 k) against one h quad
static __device__ __forceinline__ float dotq(u32x4 w, u32x4 h, float a) {
  a = fdot2(w[0], h[0], a);
  a = fdot2(w[1], h[1], a);
  a = fdot2(w[2], h[2], a);
  a = fdot2(w[3], h[3], a);
  return a;
}

// ---------------- init ----------------
__global__ void k_init(int* slotmap, float* agg, float* cnt, float* hs0) {
  int i = blockIdx.x * blockDim.x + threadIdx.x;
  int stride = gridDim.x * blockDim.x;
  for (int idx = i; idx < 4096 * 128; idx += stride) agg[idx] = 0.f;
  for (int idx = i; idx < NNODES; idx += stride) slotmap[idx] = -1;
  for (int idx = i; idx < 4096; idx += stride) cnt[idx] = 0.f;
  for (int idx = i; idx < 8192; idx += stride) hs0[idx] = 0.f;
}

// ---------------- mark needed nodes ----------------
__global__ void k_mark(const int* __restrict__ input_ids, int* __restrict__ slotmap) {
  int p = blockIdx.x * blockDim.x + threadIdx.x;
  if (p < NPOS) atomicCAS(&slotmap[input_ids[p]], -1, p);
}

// ---------------- edge pass: masked segment-sum ----------------
__global__ void k_edge(const int* __restrict__ src, const int* __restrict__ dst,
                       const float* __restrict__ ev, const float* __restrict__ emb,
                       const int* __restrict__ slotmap,
                       float* __restrict__ agg, float* __restrict__ cnt) {
  int e = blockIdx.x * 256 + threadIdx.x;
  int lane = threadIdx.x & 63;
  int d = dst[e];
  int slot = slotmap[d];
  int sn = 0; float vv = 0.f;
  if (slot >= 0) { sn = src[e]; vv = ev[e]; }
  unsigned long long m = __ballot(slot >= 0);
  while (m) {
    int j = __ffsll(m) - 1;
    m &= m - 1;
    int sl = __shfl(slot, j);
    int s2 = __shfl(sn, j);
    float v = __shfl(vv, j);
    float2 em = *(const float2*)&emb[(size_t)s2 * 128 + 2 * lane];
    atomicAdd(&agg[sl * 128 + 2 * lane],     em.x * v);
    atomicAdd(&agg[sl * 128 + 2 * lane + 1], em.y * v);
    if (lane == 0) atomicAdd(&cnt[sl], 1.f);
  }
}

// ---------------- divide by count ----------------
__global__ void k_div(float* __restrict__ agg, const float* __restrict__ cnt) {
  int i = blockIdx.x * blockDim.x + threadIdx.x;
  agg[i] /= fmaxf(cnt[i >> 7], 1.f);
}

// ---------------- fuse W_f = w_ih @ W1, bias_f ----------------
__global__ void k_fuse(const float* __restrict__ w_ih, const float* __restrict__ W1,
                       const float* __restrict__ b1, const float* __restrict__ b_ih,
                       const float* __restrict__ b_hh,
                       float* __restrict__ Wf, float* __restrict__ bf) {
  int row = blockIdx.x;
  int e = threadIdx.x;
  float acc = 0.f;
  for (int m2 = 0; m2 < 256; ++m2) acc += w_ih[row * 256 + m2] * W1[m2 * 128 + e];
  Wf[row * 128 + e] = acc;
  if (e == 0) {
    float bacc = b_ih[row] + b_hh[row];
    for (int m2 = 0; m2 < 256; ++m2) bacc += w_ih[row * 256 + m2] * b1[m2];
    bf[row] = bacc;
  }
}

// ---------------- pre-gates GEMM: preg[t][s][m][q][32d] ----------------
__global__ __launch_bounds__(256, 2) void k_pregemm(
    const float* __restrict__ hnode, const float* __restrict__ Wf,
    const float* __restrict__ bf, const int* __restrict__ slotmap,
    const int* __restrict__ input_ids, float* __restrict__ preg) {
  __shared__ float Ash[64][132];
  __shared__ float Bsh[64][132];
  __shared__ int slots[64];
  int tid = threadIdx.x;
  int bm = (blockIdx.x & 63) * 64;
  int bn = (blockIdx.x >> 6) * 64;
  if (tid < 64) slots[tid] = slotmap[input_ids[bm + tid]];
  __syncthreads();
#pragma unroll
  for (int i = 0; i < 8; ++i) {
    int idx = tid + 256 * i;
    int r = idx >> 5, c = idx & 31;
    *(float4*)&Ash[r][c * 4] = *(const float4*)&hnode[slots[r] * 128 + c * 4];
    *(float4*)&Bsh[r][c * 4] = *(const float4*)&Wf[(bn + r) * 128 + c * 4];
  }
  __syncthreads();
  int tx = tid & 15, ty = tid >> 4;
  float acc[4][4] = {};
  for (int k = 0; k < 128; k += 4) {
    float4 a[4], bb[4];
#pragma unroll
    for (int i = 0; i < 4; ++i) a[i] = *(const float4*)&Ash[tx + 16 * i][k];
#pragma unroll
    for (int j = 0; j < 4; ++j) bb[j] = *(const float4*)&Bsh[ty + 16 * j][k];
#pragma unroll
    for (int i = 0; i < 4; ++i)
#pragma unroll
      for (int j = 0; j < 4; ++j)
        acc[i][j] += a[i].x * bb[j].x + a[i].y * bb[j].y + a[i].z * bb[j].z + a[i].w * bb[j].w;
  }
#pragma unroll
  for (int j = 0; j < 4; ++j) {
    int row = bn + ty + 16 * j;
    float bias = bf[row];
    int q  = row >> 8;
    int mm = (row >> 5) & 7;
    int dl = row & 31;
#pragma unroll
    for (int i = 0; i < 4; ++i) {
      int p = bm + tx + 16 * i;
      int s = p >> 7, tt = p & 127;
      preg[(((size_t)(tt * 32 + s) * 8 + mm) * 4 + q) * 32 + dl] = acc[i][j] + bias;
    }
  }
}

// ---------------- w_hh f32 -> packed fp16 three-way images (RNE) ----------------
// k_lstm mapping (R10 geometry): tid = kseg*256 + dd owns gate rows q*256+dd
// (q=0..3), k-slice [64*kseg, 64*kseg+64) = 8 quads/gate. Quad (q, c=pair>>2):
//   q==0, c<6   -> REG    quad qr = c                (6 quads)
//   q==0, c>=6  -> LDS    lc = c-6                   (2)
//   q==1, c<7   -> LDS    lc = 2+c                   (7)   [9 LDS total]
//   q==1, c==7  -> STREAM sc = 14
//   q==2        -> STREAM sc = (c<7) ? 2c   : 15
//   q==3        -> STREAM sc = (c<7) ? 2c+1 : 16     [17 STREAM, consumption order]
__global__ void k_wcvt(const float* __restrict__ w_hh, unsigned* __restrict__ wR,
                       unsigned* __restrict__ wL, unsigned* __restrict__ wS) {
  int idx = blockIdx.x * 256 + threadIdx.x;   // 0..131071
  int row = idx >> 7;          // q*256 + dd
  int j   = idx & 127;         // pair index (k = 2j, 2j+1)
  float x0 = w_hh[(size_t)row * 256 + 2 * j];
  float x1 = w_hh[(size_t)row * 256 + 2 * j + 1];
  union { _Float16 f[2]; unsigned u; } pk;
  pk.f[0] = (_Float16)x0;
  pk.f[1] = (_Float16)x1;
  int q = row >> 8, dd = row & 255;
  int kseg = j >> 5, p = j & 31;
  int c = p >> 2, l = p & 3;
  int tid = kseg * 256 + dd;
  if (q == 0 && c < 6) {
    wR[(c * 4 + l) * 1024 + tid] = pk.u;
  } else if (q == 0) {
    wL[((c - 6) * 1024 + tid) * 4 + l] = pk.u;
  } else if (q == 1 && c < 7) {
    wL[((2 + c) * 1024 + tid) * 4 + l] = pk.u;
  } else if (q == 1) {
    wS[(14 * 1024 + tid) * 4 + l] = pk.u;
  } else if (q == 2) {
    wS[(((c < 7) ? (2 * c) : 15) * 1024 + tid) * 4 + l] = pk.u;
  } else {
    wS[(((c < 7) ? (2 * c + 1) : 16) * 1024 + tid) * 4 + l] = pk.u;
  }
}

// ---------------- LSTM: one sequence per CU; reg/LDS/L2-stream, 16 waves ----
// R10-R12 measured: 16 waves overlap VMEM at ~96% of floor; 8 waves don't
// (~2x floor). VGPR budget @1024thr = 64. This kernel = R10's exact geometry
// and epilogue, with the weight sourcing fixed to fit the budget: 6 quads in
// registers (24 words; live ~55 <= 64), 9 quads in LDS (147456 B), 17 quads
// streamed from L2 in consumption order (278 KB/step vs R10's 376 KB scratch).
// Predicted step ~2900 cyc (VMEM floor 2785 at 96% eff) ~= 1.2 us.
__global__ __launch_bounds__(1024) void k_lstm(
    const unsigned* __restrict__ wR, const unsigned* __restrict__ wL,
    const unsigned* __restrict__ wS, const float* __restrict__ preg,
    float* __restrict__ hs) {
  __shared__ __align__(16) unsigned whL[9 * 1024 * 4];   // 147456 B
  __shared__ __align__(16) unsigned h16[128];            // 512 B: 256 fp16 h
  __shared__ __align__(16) float    accb[3 * 256 * 4];   // 12288 B (16B stride)
  const int tid  = threadIdx.x;
  const int s    = blockIdx.x;
  const int kseg = tid >> 8;       // 0..3 : k-slice [64*kseg, 64*kseg+64)
  const int d    = tid & 255;
  const bool owner = (kseg == 0);

  // ---- prologue: 6 quads -> VGPRs, 9 quads -> LDS (coalesced) ----
  u32x4 rq[6];
#pragma unroll
  for (int qr = 0; qr < 6; ++qr)
#pragma unroll
    for (int l = 0; l < 4; ++l)
      rq[qr][l] = wR[(qr * 4 + l) * 1024 + tid];
  {
    const u32x4* src = (const u32x4*)wL;
    u32x4* dst = (u32x4*)whL;
#pragma unroll
    for (int lc = 0; lc < 9; ++lc)
      dst[lc * 1024 + tid] = src[lc * 1024 + tid];
  }
  if (tid < 128) h16[tid] = 0u;    // h(0) = 0 (fp16 pairs)
  float c_st = 0.f;                // cell state (owners)
  __syncthreads();

  const u32x4* hqp = (const u32x4*)h16 + kseg * 8;  // 8 h-quads for this kseg
  const u32x4* lq  = (const u32x4*)whL + tid;       // LDS quad lc at lq[lc*1024]
  const u32x4* sq  = (const u32x4*)wS + tid;        // stream quad sc at sq[sc*1024]

  for (int t = 0; t < TSTEPS; ++t) {
    // pre-gates (owners): issue early, consumed after the dots
    float pg[4] = {0.f, 0.f, 0.f, 0.f};
    if (owner) {
      const float* pb = preg + (((size_t)(t * 32 + s) * 8 + (d >> 5)) * 4) * 32
                        + (d & 31);
#pragma unroll
      for (int q = 0; q < 4; ++q) pg[q] = pb[q * 32];
    }
    // ---- dots: per c-chunk, 1 h-quad vs 4 gate quads (reg/LDS/stream) ----
    float a0 = 0.f, a1 = 0.f, a2 = 0.f, a3 = 0.f;
#pragma unroll
    for (int c = 0; c < 8; ++c) {
      u32x4 h4 = hqp[c];                               // wave-uniform broadcast
      u32x4 w0 = (c < 6) ? rq[c] : lq[(c - 6) * 1024];
      u32x4 w1 = (c < 7) ? lq[(2 + c) * 1024] : sq[14 * 1024];
      u32x4 w2 = sq[((c < 7) ? (2 * c) : 15) * 1024];
      u32x4 w3 = sq[((c < 7) ? (2 * c + 1) : 16) * 1024];
      a0 = dotq(w0, h4, a0);
      a1 = dotq(w1, h4, a1);
      a2 = dotq(w2, h4, a2);
      a3 = dotq(w3, h4, a3);
    }
    // ---- publish partials (ksegs 1..3), 16B-stride conflict-free ----
    if (!owner) {
      f32x4 r; r.x = a0; r.y = a1; r.z = a2; r.w = a3;
      *(f32x4*)&accb[((kseg - 1) * 256 + d) * 4] = r;
    }
    __syncthreads();                 // partials visible; h16 reads done
    if (owner) {
      f32x4 r0 = *(const f32x4*)&accb[(0 * 256 + d) * 4];
      f32x4 r1 = *(const f32x4*)&accb[(1 * 256 + d) * 4];
      f32x4 r2 = *(const f32x4*)&accb[(2 * 256 + d) * 4];
      float gi = a0 + r0.x + r1.x + r2.x + pg[0];
      float gf = a1 + r0.y + r1.y + r2.y + pg[1];
      float gg = a2 + r0.z + r1.z + r2.z + pg[2];
      float go = a3 + r0.w + r1.w + r2.w + pg[3];
      float si = 1.f / (1.f + expf(-gi));
      float sf = 1.f / (1.f + expf(-gf));
      float so = 1.f / (1.f + expf(-go));
      float cc = sf * c_st + si * tanhf(gg);
      float hh = so * tanhf(cc);
      c_st = cc;
      ((_Float16*)h16)[d] = (_Float16)hh;                    // next-step h (fp16)
      hs[(size_t)(t + 1) * 8192 + s * 256 + d] = hh;         // f32 history
    }
    __syncthreads();                 // new h16 + accb reuse protected
  }
}

// ---------------- final: scores, softmax, BCE, argmax ----------------
__global__ void k_final(const float* __restrict__ hs, const int* __restrict__ mask,
                        const float* __restrict__ labels, const float* __restrict__ W2,
                        const float* __restrict__ b2, float* __restrict__ out) {
  __shared__ float scores[32];
  __shared__ float errpart[8];
  int tid = threadIdx.x;
  if (tid < 32) {
    int len = 0;
    for (int t = 0; t < 128; ++t) len += mask[tid * 128 + t];
    if (len < 1) len = 1;
    const float* hl = hs + (size_t)len * 8192 + tid * 256;
    float acc = b2[0];
    for (int k = 0; k < 256; ++k) acc += hl[k] * W2[k];
    scores[tid] = acc;
  }
  __syncthreads();
  if (tid < 8) {
    float sc[4];
#pragma unroll
    for (int i = 0; i < 4; ++i) sc[i] = scores[tid * 4 + i];
    float mx = fmaxf(fmaxf(sc[0], sc[1]), fmaxf(sc[2], sc[3]));
    float ex[4], ssum = 0.f;
#pragma unroll
    for (int i = 0; i < 4; ++i) { ex[i] = expf(sc[i] - mx); ssum += ex[i]; }
    float esum = 0.f; int am = 0; float best = -1e30f;
#pragma unroll
    for (int i = 0; i < 4; ++i) {
      float p = ex[i] / ssum;
      float li = labels[tid * 4 + i];
      esum += fmaxf(p, 0.f) - p * li + log1pf(expf(-fabsf(p)));
      if (p > best) { best = p; am = i; }
    }
    errpart[tid] = esum;
    out[1 + tid] = (float)am;
  }
  __syncthreads();
  if (tid == 0) {
    float e = 0.f;
    for (int i = 0; i < 8; ++i) e += errpart[i];
    out[0] = e / 32.f;
  }
}

extern "C" void kernel_launch(void* const* d_in, const int* in_sizes, int n_in,
                              void* d_out, int out_size, void* d_ws, size_t ws_size,
                              hipStream_t stream) {
  const int*   input_ids  = (const int*)d_in[0];
  const int*   input_mask = (const int*)d_in[1];
  const float* labels     = (const float*)d_in[2];
  const int*   src        = (const int*)d_in[3];
  const int*   dst        = (const int*)d_in[4];
  const float* ev         = (const float*)d_in[5];
  const float* node_emb   = (const float*)d_in[6];
  const float* W1         = (const float*)d_in[7];
  const float* b1         = (const float*)d_in[8];
  const float* w_ih       = (const float*)d_in[9];
  const float* w_hh       = (const float*)d_in[10];
  const float* b_ih       = (const float*)d_in[11];
  const float* b_hh       = (const float*)d_in[12];
  const float* W2         = (const float*)d_in[13];
  const float* b2         = (const float*)d_in[14];
  float* out = (float*)d_out;
  char* ws = (char*)d_ws;
  int*      slotmap = (int*)(ws + OFF_SLOT);
  float*    agg     = (float*)(ws + OFF_AGG);
  float*    cnt     = (float*)(ws + OFF_CNT);
  float*    Wf      = (float*)(ws + OFF_WF);
  float*    biasf   = (float*)(ws + OFF_BIASF);
  float*    preg    = (float*)(ws + OFF_PREG);
  float*    hs      = (float*)(ws + OFF_HS);
  unsigned* wRimg   = (unsigned*)(ws + OFF_WR);
  unsigned* wLimg   = (unsigned*)(ws + OFF_WL);
  unsigned* wSimg   = (unsigned*)(ws + OFF_WS);

  hipLaunchKernelGGL(k_init,    dim3(2048), dim3(256),  0, stream, slotmap, agg, cnt, hs);
  hipLaunchKernelGGL(k_mark,    dim3(16),   dim3(256),  0, stream, input_ids, slotmap);
  hipLaunchKernelGGL(k_edge,    dim3(6250), dim3(256),  0, stream, src, dst, ev, node_emb, slotmap, agg, cnt);
  hipLaunchKernelGGL(k_div,     dim3(2048), dim3(256),  0, stream, agg, cnt);
  hipLaunchKernelGGL(k_fuse,    dim3(1024), dim3(128),  0, stream, w_ih, W1, b1, b_ih, b_hh, Wf, biasf);
  hipLaunchKernelGGL(k_pregemm, dim3(1024), dim3(256),  0, stream, agg, Wf, biasf, slotmap, input_ids, preg);
  hipLaunchKernelGGL(k_wcvt,    dim3(512),  dim3(256),  0, stream, w_hh, wRimg, wLimg, wSimg);
  hipLaunchKernelGGL(k_lstm,    dim3(NSEQ), dim3(1024), 0, stream, wRimg, wLimg, wSimg, preg, hs);
  hipLaunchKernelGGL(k_final,   dim3(1),    dim3(64),   0, stream, hs, input_mask, labels, W2, b2, out);
}